// Round 5
// baseline (838.322 us; speedup 1.0000x reference)
//
#include <hip/hip_runtime.h>

typedef __bf16 bf16x8 __attribute__((ext_vector_type(8)));
typedef __bf16 bf16x4 __attribute__((ext_vector_type(4)));
typedef float  f32x4  __attribute__((ext_vector_type(4)));
typedef int    int4v  __attribute__((ext_vector_type(4)));

#define LL    384
#define CC    128
#define NROW  (LL * LL)   // 147456

#define MFMA16(a, b, c) __builtin_amdgcn_mfma_f32_16x16x32_bf16((a), (b), (c), 0, 0, 0)

// fp32 -> bf16x8 fragment load (8 consecutive floats, 32B)
__device__ __forceinline__ bf16x8 cvt8(const float* p) {
    f32x4 a = *reinterpret_cast<const f32x4*>(p);
    f32x4 b = *reinterpret_cast<const f32x4*>(p + 4);
    bf16x8 r;
    r[0] = (__bf16)a[0]; r[1] = (__bf16)a[1]; r[2] = (__bf16)a[2]; r[3] = (__bf16)a[3];
    r[4] = (__bf16)b[0]; r[5] = (__bf16)b[1]; r[6] = (__bf16)b[2]; r[7] = (__bf16)b[3];
    return r;
}
__device__ __forceinline__ bf16x8 ld_ws(const __bf16* p) {   // ws is bf16
    return __builtin_bit_cast(bf16x8, *reinterpret_cast<const int4v*>(p));
}
__device__ __forceinline__ float sigmf(float x) { return 1.f / (1.f + __expf(-x)); }

// ---------------------------------------------------------------------------
// k_proj: per-row x (fp32) -> channel chunk [c_base, c_base+c_count) of
// pl/pr, stored channel-major bf16 in ws: pl_c[cc][r], pr_c[cc][r].
// Full GEMMs+LN always (LN needs all 128 channels); only chunk stored.
// ---------------------------------------------------------------------------
__global__ __launch_bounds__(256, 2) void k_proj(
    const float* __restrict__ pf, const float* __restrict__ rmask,
    const float* __restrict__ lp_w, const float* __restrict__ lp_b,
    const float* __restrict__ lp_g, const float* __restrict__ lp_be,
    const float* __restrict__ rp_w, const float* __restrict__ rp_b,
    const float* __restrict__ rp_g, const float* __restrict__ rp_be,
    const float* __restrict__ lg_w, const float* __restrict__ lg_b,
    const float* __restrict__ rg_w, const float* __restrict__ rg_b,
    __bf16* __restrict__ pl_c, __bf16* __restrict__ pr_c,
    int c_base, int c_count)
{
    const int tid  = threadIdx.x;
    const int wave = tid >> 6;
    const int lane = tid & 63;
    const int n16  = lane & 15;
    const int quad = lane >> 4;
    const int rowbase = blockIdx.x * 64 + wave * 16;
    const int r_a = rowbase + n16;

    bf16x8 xf[4];
    #pragma unroll
    for (int ks = 0; ks < 4; ++ks)
        xf[ks] = cvt8(pf + (size_t)r_a * CC + ks * 32 + quad * 8);

    const int rd   = rowbase + quad * 4;          // first of 4 D rows
    const int i_id = rd / LL;
    const int k_id = rd - i_id * LL;              // rd%4==0 -> k_id+3 < 384
    float mrow[4];
    {
        float mi = rmask[i_id];
        #pragma unroll
        for (int g = 0; g < 4; ++g) mrow[g] = mi * rmask[k_id + g];
    }

    f32x4 acc[8], sg[8];

    auto gemm_std = [&](const float* __restrict__ w, const float* __restrict__ b) {
        #pragma unroll
        for (int nt = 0; nt < 8; ++nt) acc[nt] = f32x4{0.f, 0.f, 0.f, 0.f};
        #pragma unroll
        for (int ks = 0; ks < 4; ++ks) {
            #pragma unroll
            for (int nt = 0; nt < 8; ++nt) {
                bf16x8 bf = cvt8(w + (size_t)(nt * 16 + n16) * CC + ks * 32 + quad * 8);
                acc[nt] = MFMA16(xf[ks], bf, acc[nt]);
            }
        }
        #pragma unroll
        for (int nt = 0; nt < 8; ++nt) {
            float bias = b[nt * 16 + n16];
            #pragma unroll
            for (int g = 0; g < 4; ++g) acc[nt][g] += bias;
        }
    };

    auto ln_comb_store = [&](const float* __restrict__ gv, const float* __restrict__ bv,
                             __bf16* __restrict__ dst) {
        float s[4] = {0.f, 0.f, 0.f, 0.f}, ss[4] = {0.f, 0.f, 0.f, 0.f};
        #pragma unroll
        for (int nt = 0; nt < 8; ++nt)
            #pragma unroll
            for (int g = 0; g < 4; ++g) { float v = acc[nt][g]; s[g] += v; ss[g] += v * v; }
        #pragma unroll
        for (int m = 1; m < 16; m <<= 1) {
            #pragma unroll
            for (int g = 0; g < 4; ++g) {
                s[g]  += __shfl_xor(s[g],  m, 64);
                ss[g] += __shfl_xor(ss[g], m, 64);
            }
        }
        float mean[4], rstd[4];
        #pragma unroll
        for (int g = 0; g < 4; ++g) {
            mean[g] = s[g] * (1.f / 128.f);
            float var = ss[g] * (1.f / 128.f) - mean[g] * mean[g];
            rstd[g] = rsqrtf(fmaxf(var, 0.f) + 1e-5f);
        }
        #pragma unroll
        for (int nt = 0; nt < 8; ++nt) {
            int c = nt * 16 + n16;
            if (c < c_base || c >= c_base + c_count) continue;  // uniform per nt
            float ga = gv[c], be = bv[c];
            bf16x4 o;
            #pragma unroll
            for (int g = 0; g < 4; ++g) {
                float v = (acc[nt][g] - mean[g]) * rstd[g] * ga + be;
                v *= mrow[g] * sg[nt][g];
                o[g] = (__bf16)v;
            }
            *reinterpret_cast<bf16x4*>(dst + (size_t)(c - c_base) * NROW + rd) = o;
        }
    };

    gemm_std(lg_w, lg_b);
    #pragma unroll
    for (int nt = 0; nt < 8; ++nt)
        #pragma unroll
        for (int g = 0; g < 4; ++g) sg[nt][g] = sigmf(acc[nt][g]);
    gemm_std(lp_w, lp_b);
    ln_comb_store(lp_g, lp_be, pl_c);

    gemm_std(rg_w, rg_b);
    #pragma unroll
    for (int nt = 0; nt < 8; ++nt)
        #pragma unroll
        for (int g = 0; g < 4; ++g) sg[nt][g] = sigmf(acc[nt][g]);
    gemm_std(rp_w, rp_b);
    ln_comb_store(rp_g, rp_be, pr_c);
}

// ---------------------------------------------------------------------------
// k_einsum<CPW>: block = 16x16 (i,j) tile x (4*CPW) channels; wave w owns
// chunk-local channels cl0..cl0+CPW. Writes pre-LN T (fp32) into d_out[r][c].
// ---------------------------------------------------------------------------
template<int CPW>
__global__ __launch_bounds__(256, 2) void k_einsum(
    const __bf16* __restrict__ pl_c, const __bf16* __restrict__ pr_c,
    int c_base, float* __restrict__ out)
{
    const int tid  = threadIdx.x;
    const int wave = tid >> 6, lane = tid & 63;
    const int n16  = lane & 15, quad = lane >> 4;
    const int i0   = blockIdx.x * 16;
    const int j0   = blockIdx.y * 16;
    const int cl0  = blockIdx.z * (4 * CPW) + wave * CPW;

    f32x4 acc[CPW];
    #pragma unroll
    for (int t = 0; t < CPW; ++t) acc[t] = f32x4{0.f, 0.f, 0.f, 0.f};

    #pragma unroll 4
    for (int t = 0; t < CPW; ++t) {
        const int cl = cl0 + t;
        const __bf16* Ab = pl_c + (size_t)cl * NROW + (size_t)(i0 + n16) * LL;
        const __bf16* Bb = pr_c + (size_t)cl * NROW + (size_t)(j0 + n16) * LL;
        #pragma unroll
        for (int kt = 0; kt < 12; ++kt) {
            bf16x8 af = ld_ws(Ab + kt * 32 + quad * 8);
            bf16x8 bf = ld_ws(Bb + kt * 32 + quad * 8);
            acc[t] = MFMA16(af, bf, acc[t]);
        }
    }

    // D: m(i)=quad*4+g, n(j)=n16. Thread stores CPW consecutive c per row.
    const int cg0 = c_base + cl0;
    #pragma unroll
    for (int g = 0; g < 4; ++g) {
        const size_t r_glob = (size_t)(i0 + quad * 4 + g) * LL + (j0 + n16);
        float* dst = out + r_glob * CC + cg0;
        #pragma unroll
        for (int h = 0; h < CPW / 4; ++h) {
            f32x4 o;
            #pragma unroll
            for (int q = 0; q < 4; ++q) o[q] = acc[h * 4 + q][g];
            *reinterpret_cast<f32x4*>(dst + h * 4) = o;
        }
    }
}

// ---------------------------------------------------------------------------
// k_final: row-wise, in place on d_out (fp32):
//   out[r][:] = (LN(T[r]) @ ow^T + ob) * sigmoid(pf[r] @ og_w^T + og_b)
// Each row is read & written only by its own wave; reads precede stores.
// ---------------------------------------------------------------------------
__global__ __launch_bounds__(256, 2) void k_final(
    float* out, const float* __restrict__ pf,
    const float* __restrict__ ol_g, const float* __restrict__ ol_be,
    const float* __restrict__ ow,   const float* __restrict__ ob,
    const float* __restrict__ og_w, const float* __restrict__ og_b)
{
    const int tid  = threadIdx.x;
    const int wave = tid >> 6, lane = tid & 63;
    const int n16  = lane & 15, quad = lane >> 4;
    const int r    = blockIdx.x * 64 + wave * 16 + n16;

    // T fragments (fp32, own data) + pf fragments (fp32 -> bf16)
    f32x4 tf[4][2];
    bf16x8 pff[4];
    #pragma unroll
    for (int ks = 0; ks < 4; ++ks) {
        const float* tp = out + (size_t)r * CC + ks * 32 + quad * 8;
        tf[ks][0] = *reinterpret_cast<const f32x4*>(tp);
        tf[ks][1] = *reinterpret_cast<const f32x4*>(tp + 4);
        pff[ks]   = cvt8(pf + (size_t)r * CC + ks * 32 + quad * 8);
    }

    // LN stats over the row's 128 channels (32 per thread, reduce over quads)
    float s = 0.f, ss = 0.f;
    #pragma unroll
    for (int ks = 0; ks < 4; ++ks)
        #pragma unroll
        for (int h = 0; h < 2; ++h)
            #pragma unroll
            for (int q = 0; q < 4; ++q) { float f = tf[ks][h][q]; s += f; ss += f * f; }
    s += __shfl_xor(s, 16, 64);  ss += __shfl_xor(ss, 16, 64);
    s += __shfl_xor(s, 32, 64);  ss += __shfl_xor(ss, 32, 64);
    const float mean = s * (1.f / 128.f);
    const float rstd = rsqrtf(fmaxf(ss * (1.f / 128.f) - mean * mean, 0.f) + 1e-5f);

    bf16x8 xn[4];
    #pragma unroll
    for (int ks = 0; ks < 4; ++ks) {
        const int cb = ks * 32 + quad * 8;
        bf16x8 rv;
        #pragma unroll
        for (int h = 0; h < 2; ++h)
            #pragma unroll
            for (int q = 0; q < 4; ++q)
                rv[h * 4 + q] = (__bf16)((tf[ks][h][q] - mean) * rstd * ol_g[cb + h * 4 + q]
                                         + ol_be[cb + h * 4 + q]);
        xn[ks] = rv;
    }

    // Two swapped-operand GEMMs: A = weight rows (m = c_out), B = row frags.
    f32x4 ao[8], ag[8];
    #pragma unroll
    for (int mt = 0; mt < 8; ++mt) { ao[mt] = f32x4{0.f,0.f,0.f,0.f}; ag[mt] = f32x4{0.f,0.f,0.f,0.f}; }
    #pragma unroll
    for (int ks = 0; ks < 4; ++ks) {
        #pragma unroll
        for (int mt = 0; mt < 8; ++mt) {
            bf16x8 aw  = cvt8(ow   + (size_t)(mt * 16 + n16) * CC + ks * 32 + quad * 8);
            bf16x8 agw = cvt8(og_w + (size_t)(mt * 16 + n16) * CC + ks * 32 + quad * 8);
            ao[mt] = MFMA16(aw,  xn[ks],  ao[mt]);
            ag[mt] = MFMA16(agw, pff[ks], ag[mt]);
        }
    }

    // D: row = c_out local (quad*4+g), col n16 = row index (matches r)
    #pragma unroll
    for (int mt = 0; mt < 8; ++mt) {
        const int c0 = mt * 16 + quad * 4;
        f32x4 o;
        #pragma unroll
        for (int g = 0; g < 4; ++g) {
            float gate = sigmf(ag[mt][g] + og_b[c0 + g]);
            o[g] = (ao[mt][g] + ob[c0 + g]) * gate;
        }
        *reinterpret_cast<f32x4*>(out + (size_t)r * CC + c0) = o;
    }
}

// ---------------------------------------------------------------------------
// Sentinel: ws too small -> out[0]=1000, rest 0 (finite err ~1000 = signal)
// ---------------------------------------------------------------------------
__global__ void k_sentinel(float* out, int n) {
    int i = blockIdx.x * blockDim.x + threadIdx.x;
    if (i < n) out[i] = (i == 0) ? 1000.0f : 0.0f;
}

// ---------------------------------------------------------------------------
extern "C" void kernel_launch(void* const* d_in, const int* in_sizes, int n_in,
                              void* d_out, int out_size, void* d_ws, size_t ws_size,
                              hipStream_t stream)
{
    const float* pf    = (const float*)d_in[0];
    const float* rmask = (const float*)d_in[1];
    const float* lp_w  = (const float*)d_in[2];
    const float* lp_b  = (const float*)d_in[3];
    const float* lp_g  = (const float*)d_in[4];
    const float* lp_be = (const float*)d_in[5];
    const float* rp_w  = (const float*)d_in[6];
    const float* rp_b  = (const float*)d_in[7];
    const float* rp_g  = (const float*)d_in[8];
    const float* rp_be = (const float*)d_in[9];
    const float* lg_w  = (const float*)d_in[10];
    const float* lg_b  = (const float*)d_in[11];
    const float* rg_w  = (const float*)d_in[12];
    const float* rg_b  = (const float*)d_in[13];
    const float* og_w  = (const float*)d_in[14];
    const float* og_b  = (const float*)d_in[15];
    const float* ol_g  = (const float*)d_in[16];
    const float* ol_be = (const float*)d_in[17];
    const float* ow    = (const float*)d_in[18];
    const float* ob    = (const float*)d_in[19];
    float* out = (float*)d_out;

    // ws need: 2 bf16 buffers of CH x NROW = CH*NROW*4 bytes
    auto need = [](int CH) { return (size_t)CH * NROW * 4; };
    const int CH = (ws_size >= need(128)) ? 128 :
                   (ws_size >= need(64))  ?  64 :
                   (ws_size >= need(32))  ?  32 : 0;

    if (CH == 0) {
        k_sentinel<<<(out_size + 255) / 256, 256, 0, stream>>>(out, out_size);
        return;
    }

    __bf16* pl_c = (__bf16*)d_ws;
    __bf16* pr_c = pl_c + (size_t)CH * NROW;
    const int passes = 128 / CH;

    for (int p = 0; p < passes; ++p) {
        const int c_base = p * CH;
        k_proj<<<NROW / 64, 256, 0, stream>>>(pf, rmask,
            lp_w, lp_b, lp_g, lp_be, rp_w, rp_b, rp_g, rp_be,
            lg_w, lg_b, rg_w, rg_b, pl_c, pr_c, c_base, CH);
        if (CH >= 64)
            k_einsum<16><<<dim3(LL / 16, LL / 16, CH / 64), 256, 0, stream>>>(
                pl_c, pr_c, c_base, out);
        else
            k_einsum<8><<<dim3(LL / 16, LL / 16, 1), 256, 0, stream>>>(
                pl_c, pr_c, c_base, out);
    }

    k_final<<<NROW / 64, 256, 0, stream>>>(out, pf,
        ol_g, ol_be, ow, ob, og_w, og_b);
}

// Round 6
// 487.492 us; speedup vs baseline: 1.7197x; 1.7197x over previous
//
#include <hip/hip_runtime.h>

typedef __bf16 bf16x8 __attribute__((ext_vector_type(8)));
typedef __bf16 bf16x4 __attribute__((ext_vector_type(4)));
typedef float  f32x4  __attribute__((ext_vector_type(4)));
typedef int    int4v  __attribute__((ext_vector_type(4)));

#define LL    384
#define CC    128
#define NROW  (LL * LL)   // 147456

#define MFMA16(a, b, c) __builtin_amdgcn_mfma_f32_16x16x32_bf16((a), (b), (c), 0, 0, 0)

__device__ __forceinline__ bf16x8 cvt8(const float* p) {
    f32x4 a = *reinterpret_cast<const f32x4*>(p);
    f32x4 b = *reinterpret_cast<const f32x4*>(p + 4);
    bf16x8 r;
    r[0] = (__bf16)a[0]; r[1] = (__bf16)a[1]; r[2] = (__bf16)a[2]; r[3] = (__bf16)a[3];
    r[4] = (__bf16)b[0]; r[5] = (__bf16)b[1]; r[6] = (__bf16)b[2]; r[7] = (__bf16)b[3];
    return r;
}
__device__ __forceinline__ bf16x8 ld_ws(const __bf16* p) {
    return __builtin_bit_cast(bf16x8, *reinterpret_cast<const int4v*>(p));
}
__device__ __forceinline__ float sigmf(float x) { return 1.f / (1.f + __expf(-x)); }

// ---------------------------------------------------------------------------
// Stage a 128x128 fp32 weight into LDS as bf16 MFMA fragments, lane-contiguous:
//   frag(ks,nt) for lane L lives at dst[((ks*8+nt)*64 + L)*8 .. +8]  (16 B)
//   element (c,k): nt=c>>4, n16=c&15, ks=k>>5, quad=(k>>3)&3, lane=quad*16+n16
// Reads are then conflict-free ds_read_b128 (wave reads 1 KB contiguous).
// ---------------------------------------------------------------------------
__device__ __forceinline__ void stage_weight(const float* __restrict__ w,
                                             __bf16* dst, int tid) {
    const int c   = tid >> 1;
    const int k0  = (tid & 1) * 64;
    const int nt  = c >> 4;
    const int n16 = c & 15;
    #pragma unroll
    for (int u = 0; u < 8; ++u) {
        const int k    = k0 + u * 8;
        const int ks   = k >> 5;
        const int quad = (k >> 3) & 3;
        bf16x8 v = cvt8(w + c * CC + k);
        *reinterpret_cast<int4v*>(dst + ((ks * 8 + nt) * 64 + quad * 16 + n16) * 8) =
            __builtin_bit_cast(int4v, v);
    }
}
__device__ __forceinline__ bf16x8 wfrag(const __bf16* base, int ks, int nt, int lane) {
    return ld_ws(base + ((ks * 8 + nt) * 64 + lane) * 8);
}

// ---------------------------------------------------------------------------
// k_proj: 128 rows/block (grid 1152). Two phases (left, right); each stages
// {gate_w, proj_w} as bf16 fragments in 64 KB LDS, then per wave (32 rows =
// 2 row-groups): gate GEMM -> sigmoid -> proj GEMM -> LN -> masked store to
// channel-major ws. x fragments live in registers across all 4 GEMMs.
// ---------------------------------------------------------------------------
__global__ __launch_bounds__(256, 2) void k_proj(
    const float* __restrict__ pf, const float* __restrict__ rmask,
    const float* __restrict__ lp_w, const float* __restrict__ lp_b,
    const float* __restrict__ lp_g, const float* __restrict__ lp_be,
    const float* __restrict__ rp_w, const float* __restrict__ rp_b,
    const float* __restrict__ rp_g, const float* __restrict__ rp_be,
    const float* __restrict__ lg_w, const float* __restrict__ lg_b,
    const float* __restrict__ rg_w, const float* __restrict__ rg_b,
    __bf16* __restrict__ pl_c, __bf16* __restrict__ pr_c)
{
    __shared__ __bf16 wl[2 * 16384];       // 65536 B

    const int tid  = threadIdx.x;
    const int wave = tid >> 6, lane = tid & 63;
    const int n16  = lane & 15, quad = lane >> 4;
    const int rowblock = blockIdx.x * 128 + wave * 32;

    // x fragments for 2 row-groups
    bf16x8 xf[2][4];
    #pragma unroll
    for (int rg = 0; rg < 2; ++rg) {
        const int r_a = rowblock + rg * 16 + n16;
        #pragma unroll
        for (int ks = 0; ks < 4; ++ks)
            xf[rg][ks] = cvt8(pf + (size_t)r_a * CC + ks * 32 + quad * 8);
    }

    // mask per row-group (D rows: rowblock + rg*16 + quad*4 + g)
    float mrow[2][4];
    #pragma unroll
    for (int rg = 0; rg < 2; ++rg) {
        const int rd   = rowblock + rg * 16 + quad * 4;
        const int i_id = rd / LL;
        const int k_id = rd - i_id * LL;      // rd%4==0 -> k_id+3 < 384
        float mi = rmask[i_id];
        #pragma unroll
        for (int g = 0; g < 4; ++g) mrow[rg][g] = mi * rmask[k_id + g];
    }

    auto phase = [&](const float* gw, const float* gb,
                     const float* pw, const float* pb,
                     const float* gamma, const float* beta,
                     __bf16* dst) {
        stage_weight(gw, wl, tid);
        stage_weight(pw, wl + 16384, tid);
        __syncthreads();

        f32x4 acc[2][8];
        // gate GEMM
        #pragma unroll
        for (int rg = 0; rg < 2; ++rg)
            #pragma unroll
            for (int nt = 0; nt < 8; ++nt) acc[rg][nt] = f32x4{0.f, 0.f, 0.f, 0.f};
        #pragma unroll
        for (int ks = 0; ks < 4; ++ks)
            #pragma unroll
            for (int nt = 0; nt < 8; ++nt) {
                bf16x8 wf = wfrag(wl, ks, nt, lane);
                #pragma unroll
                for (int rg = 0; rg < 2; ++rg)
                    acc[rg][nt] = MFMA16(xf[rg][ks], wf, acc[rg][nt]);
            }
        bf16x4 sg[2][8];
        #pragma unroll
        for (int rg = 0; rg < 2; ++rg)
            #pragma unroll
            for (int nt = 0; nt < 8; ++nt) {
                float bias = gb[nt * 16 + n16];
                #pragma unroll
                for (int g = 0; g < 4; ++g)
                    sg[rg][nt][g] = (__bf16)sigmf(acc[rg][nt][g] + bias);
            }
        // proj GEMM
        #pragma unroll
        for (int rg = 0; rg < 2; ++rg)
            #pragma unroll
            for (int nt = 0; nt < 8; ++nt) acc[rg][nt] = f32x4{0.f, 0.f, 0.f, 0.f};
        #pragma unroll
        for (int ks = 0; ks < 4; ++ks)
            #pragma unroll
            for (int nt = 0; nt < 8; ++nt) {
                bf16x8 wf = wfrag(wl + 16384, ks, nt, lane);
                #pragma unroll
                for (int rg = 0; rg < 2; ++rg)
                    acc[rg][nt] = MFMA16(xf[rg][ks], wf, acc[rg][nt]);
            }
        // bias + LN + combine + store
        #pragma unroll
        for (int rg = 0; rg < 2; ++rg) {
            #pragma unroll
            for (int nt = 0; nt < 8; ++nt) {
                float bias = pb[nt * 16 + n16];
                #pragma unroll
                for (int g = 0; g < 4; ++g) acc[rg][nt][g] += bias;
            }
            float s[4] = {0.f,0.f,0.f,0.f}, ss[4] = {0.f,0.f,0.f,0.f};
            #pragma unroll
            for (int nt = 0; nt < 8; ++nt)
                #pragma unroll
                for (int g = 0; g < 4; ++g) { float v = acc[rg][nt][g]; s[g] += v; ss[g] += v * v; }
            #pragma unroll
            for (int m = 1; m < 16; m <<= 1)
                #pragma unroll
                for (int g = 0; g < 4; ++g) {
                    s[g]  += __shfl_xor(s[g],  m, 64);
                    ss[g] += __shfl_xor(ss[g], m, 64);
                }
            float mean[4], rstd[4];
            #pragma unroll
            for (int g = 0; g < 4; ++g) {
                mean[g] = s[g] * (1.f / 128.f);
                float var = ss[g] * (1.f / 128.f) - mean[g] * mean[g];
                rstd[g] = rsqrtf(fmaxf(var, 0.f) + 1e-5f);
            }
            const int rd = rowblock + rg * 16 + quad * 4;
            #pragma unroll
            for (int nt = 0; nt < 8; ++nt) {
                const int c = nt * 16 + n16;
                float ga = gamma[c], be = beta[c];
                bf16x4 o;
                #pragma unroll
                for (int g = 0; g < 4; ++g) {
                    float v = (acc[rg][nt][g] - mean[g]) * rstd[g] * ga + be;
                    v *= mrow[rg][g] * (float)sg[rg][nt][g];
                    o[g] = (__bf16)v;
                }
                *reinterpret_cast<bf16x4*>(dst + (size_t)c * NROW + rd) = o;
            }
        }
        __syncthreads();   // protect wl before next phase restages
    };

    phase(lg_w, lg_b, lp_w, lp_b, lp_g, lp_be, pl_c);
    phase(rg_w, rg_b, rp_w, rp_b, rp_g, rp_be, pr_c);
}

// ---------------------------------------------------------------------------
// k_einsum: grid (6,6,16). Block = 64x64 (i,j) tile x 8 channels; wave w owns
// j-quarter w*16. Direct global reads from ws (fi rows shared by all 4 waves
// -> L1 reuse). Per-thread acc over 8 channels -> 32-B contiguous stores of
// pre-LN T (fp32) into d_out[r][c0..c0+8].
// ---------------------------------------------------------------------------
__global__ __launch_bounds__(256, 2) void k_einsum(
    const __bf16* __restrict__ pl_c, const __bf16* __restrict__ pr_c,
    float* __restrict__ out)
{
    const int tid  = threadIdx.x;
    const int wave = tid >> 6, lane = tid & 63;
    const int n16  = lane & 15, quad = lane >> 4;
    const int i0   = blockIdx.x * 64;
    const int jw   = blockIdx.y * 64 + wave * 16;
    const int c0   = blockIdx.z * 8;

    size_t off_i[4];
    #pragma unroll
    for (int t = 0; t < 4; ++t)
        off_i[t] = (size_t)(i0 + t * 16 + n16) * LL + quad * 8;
    const size_t off_j = (size_t)(jw + n16) * LL + quad * 8;

    f32x4 acc[8][4];
    #pragma unroll
    for (int c = 0; c < 8; ++c)
        #pragma unroll
        for (int t = 0; t < 4; ++t) acc[c][t] = f32x4{0.f, 0.f, 0.f, 0.f};

    #pragma unroll
    for (int c = 0; c < 8; ++c) {
        const __bf16* Pb = pl_c + (size_t)(c0 + c) * NROW;
        const __bf16* Qb = pr_c + (size_t)(c0 + c) * NROW + off_j;
        #pragma unroll
        for (int kt = 0; kt < 12; ++kt) {
            bf16x8 fj = ld_ws(Qb + kt * 32);
            #pragma unroll
            for (int t = 0; t < 4; ++t) {
                bf16x8 fi = ld_ws(Pb + off_i[t] + kt * 32);
                acc[c][t] = MFMA16(fi, fj, acc[c][t]);   // D: m=i, n=j
            }
        }
    }

    // store: thread owns (i = i0+t*16+quad*4+g, j = jw+n16), 8 consecutive c
    #pragma unroll
    for (int t = 0; t < 4; ++t)
        #pragma unroll
        for (int g = 0; g < 4; ++g) {
            const int i = i0 + t * 16 + quad * 4 + g;
            float* dst = out + ((size_t)i * LL + jw + n16) * CC + c0;
            f32x4 lo, hi;
            #pragma unroll
            for (int q = 0; q < 4; ++q) { lo[q] = acc[q][t][g]; hi[q] = acc[4 + q][t][g]; }
            *reinterpret_cast<f32x4*>(dst)     = lo;
            *reinterpret_cast<f32x4*>(dst + 4) = hi;
        }
}

// ---------------------------------------------------------------------------
// k_final: 128 rows/block (grid 1152), in place on d_out:
//   out[r][:] = (LN(T[r]) @ ow^T + ob) * sigmoid(pf[r] @ og_w^T + og_b)
// ow/og_w staged once per block as bf16 fragments in 64 KB LDS.
// Row r is read and written only by its own threads; reads precede stores.
// ---------------------------------------------------------------------------
__global__ __launch_bounds__(256, 2) void k_final(
    float* out, const float* __restrict__ pf,
    const float* __restrict__ ol_g, const float* __restrict__ ol_be,
    const float* __restrict__ ow,   const float* __restrict__ ob,
    const float* __restrict__ og_w, const float* __restrict__ og_b)
{
    __shared__ __bf16 wl[2 * 16384];       // 65536 B
    const int tid  = threadIdx.x;
    const int wave = tid >> 6, lane = tid & 63;
    const int n16  = lane & 15, quad = lane >> 4;
    const int rowblock = blockIdx.x * 128 + wave * 32;

    stage_weight(ow,   wl,         tid);
    stage_weight(og_w, wl + 16384, tid);
    __syncthreads();

    #pragma unroll
    for (int rg = 0; rg < 2; ++rg) {
        const int r = rowblock + rg * 16 + n16;

        f32x4 tf[8];
        bf16x8 pff[4];
        #pragma unroll
        for (int ks = 0; ks < 4; ++ks) {
            const float* tp = out + (size_t)r * CC + ks * 32 + quad * 8;
            tf[2 * ks]     = *reinterpret_cast<const f32x4*>(tp);
            tf[2 * ks + 1] = *reinterpret_cast<const f32x4*>(tp + 4);
            pff[ks] = cvt8(pf + (size_t)r * CC + ks * 32 + quad * 8);
        }

        float s = 0.f, ss = 0.f;
        #pragma unroll
        for (int h = 0; h < 8; ++h)
            #pragma unroll
            for (int q = 0; q < 4; ++q) { float f = tf[h][q]; s += f; ss += f * f; }
        s += __shfl_xor(s, 16, 64);  ss += __shfl_xor(ss, 16, 64);
        s += __shfl_xor(s, 32, 64);  ss += __shfl_xor(ss, 32, 64);
        const float mean = s * (1.f / 128.f);
        const float rstd = rsqrtf(fmaxf(ss * (1.f / 128.f) - mean * mean, 0.f) + 1e-5f);

        bf16x8 xn[4];
        #pragma unroll
        for (int ks = 0; ks < 4; ++ks) {
            const int cb = ks * 32 + quad * 8;
            f32x4 g0 = *reinterpret_cast<const f32x4*>(ol_g + cb);
            f32x4 g1 = *reinterpret_cast<const f32x4*>(ol_g + cb + 4);
            f32x4 b0 = *reinterpret_cast<const f32x4*>(ol_be + cb);
            f32x4 b1 = *reinterpret_cast<const f32x4*>(ol_be + cb + 4);
            bf16x8 rv;
            #pragma unroll
            for (int q = 0; q < 4; ++q) {
                rv[q]     = (__bf16)((tf[2 * ks][q]     - mean) * rstd * g0[q] + b0[q]);
                rv[4 + q] = (__bf16)((tf[2 * ks + 1][q] - mean) * rstd * g1[q] + b1[q]);
            }
            xn[ks] = rv;
        }

        f32x4 ao[8], ag[8];
        #pragma unroll
        for (int mt = 0; mt < 8; ++mt) { ao[mt] = f32x4{0.f,0.f,0.f,0.f}; ag[mt] = f32x4{0.f,0.f,0.f,0.f}; }
        #pragma unroll
        for (int ks = 0; ks < 4; ++ks)
            #pragma unroll
            for (int mt = 0; mt < 8; ++mt) {
                bf16x8 awf = wfrag(wl,         ks, mt, lane);
                bf16x8 gwf = wfrag(wl + 16384, ks, mt, lane);
                ao[mt] = MFMA16(awf, xn[ks],  ao[mt]);   // m = c_out, n = row
                ag[mt] = MFMA16(gwf, pff[ks], ag[mt]);
            }

        #pragma unroll
        for (int mt = 0; mt < 8; ++mt) {
            const int c0 = mt * 16 + quad * 4;
            f32x4 bb = *reinterpret_cast<const f32x4*>(ob + c0);
            f32x4 gb = *reinterpret_cast<const f32x4*>(og_b + c0);
            f32x4 o;
            #pragma unroll
            for (int g = 0; g < 4; ++g) {
                float gate = sigmf(ag[mt][g] + gb[g]);
                o[g] = (ao[mt][g] + bb[g]) * gate;
            }
            *reinterpret_cast<f32x4*>(out + (size_t)r * CC + c0) = o;
        }
    }
}

// ---------------------------------------------------------------------------
extern "C" void kernel_launch(void* const* d_in, const int* in_sizes, int n_in,
                              void* d_out, int out_size, void* d_ws, size_t ws_size,
                              hipStream_t stream)
{
    const float* pf    = (const float*)d_in[0];
    const float* rmask = (const float*)d_in[1];
    const float* lp_w  = (const float*)d_in[2];
    const float* lp_b  = (const float*)d_in[3];
    const float* lp_g  = (const float*)d_in[4];
    const float* lp_be = (const float*)d_in[5];
    const float* rp_w  = (const float*)d_in[6];
    const float* rp_b  = (const float*)d_in[7];
    const float* rp_g  = (const float*)d_in[8];
    const float* rp_be = (const float*)d_in[9];
    const float* lg_w  = (const float*)d_in[10];
    const float* lg_b  = (const float*)d_in[11];
    const float* rg_w  = (const float*)d_in[12];
    const float* rg_b  = (const float*)d_in[13];
    const float* og_w  = (const float*)d_in[14];
    const float* og_b  = (const float*)d_in[15];
    const float* ol_g  = (const float*)d_in[16];
    const float* ol_be = (const float*)d_in[17];
    const float* ow    = (const float*)d_in[18];
    const float* ob    = (const float*)d_in[19];
    float* out = (float*)d_out;

    __bf16* pl_c = (__bf16*)d_ws;                 // [128][147456] bf16
    __bf16* pr_c = pl_c + (size_t)CC * NROW;      // [128][147456] bf16

    k_proj<<<NROW / 128, 256, 0, stream>>>(pf, rmask,
        lp_w, lp_b, lp_g, lp_be, rp_w, rp_b, rp_g, rp_be,
        lg_w, lg_b, rg_w, rg_b, pl_c, pr_c);
    k_einsum<<<dim3(LL / 64, LL / 64, CC / 8), 256, 0, stream>>>(pl_c, pr_c, out);
    k_final<<<NROW / 128, 256, 0, stream>>>(out, pf,
        ol_g, ol_be, ow, ob, og_w, og_b);
}